// Round 8
// baseline (443.065 us; speedup 1.0000x reference)
//
#include <hip/hip_runtime.h>
#include <hip/hip_bf16.h>
#include <float.h>

// Problem constants (from reference)
#define N_NODES 20000
#define LATENT  512
#define HID     256
#define OUT_C   128
#define HEADS   2
#define HC      256   // HEADS*OUT_C
#define NEG_SLOPE 0.2f

typedef _Float16 half8 __attribute__((ext_vector_type(8)));  // 8 f16 = 4 VGPRs
typedef __attribute__((ext_vector_type(4))) float f32x4;
typedef __attribute__((ext_vector_type(2))) float f32x2;

// ---------------------------------------------------------------------------
__device__ __forceinline__ ushort f2h(float v) {
    _Float16 h = (_Float16)v;
    return *(ushort*)&h;
}
__device__ __forceinline__ float h2f(ushort u) {
    _Float16 h = *(_Float16*)&u;
    return (float)h;
}

// ---- fp8 e4m3 (OCP) encode/decode. Prefer HW cvt; exact bit-trick fallback.
#if __has_builtin(__builtin_amdgcn_cvt_pk_fp8_f32) && __has_builtin(__builtin_amdgcn_cvt_pk_f32_fp8)
#define FP8_HW 1
#else
#define FP8_HW 0
#endif

__device__ __forceinline__ uint f32_to_e4m3(float v) {
#if FP8_HW
    return (uint)(__builtin_amdgcn_cvt_pk_fp8_f32(v, v, 0, false) & 0xff);
#else
    _Float16 hf = (_Float16)(v * 0.00390625f);   // *2^-8
    uint hb = *(ushort*)&hf;
    uint s = (hb >> 8) & 0x80;
    uint mag = hb & 0x7fff;
    mag = (mag + 0x3f + ((mag >> 7) & 1)) >> 7;  // RNE 10->3 mantissa bits
    if (mag > 0x7e) mag = 0x7e;
    return s | mag;
#endif
}

// ---------------------------------------------------------------------------
// R18: fused MLP v3 -- BARRIER ELIMINATION. R17 counters: Occupancy 19.6%
// (313 blocks ~ 1.2/CU, so the 2-blocks/CU LDS fit bought nothing),
// MfmaUtil 12.9%, HBM 6% -> the ~76-barrier lockstep staging chain IS the
// kernel. Fix: weights (256 KB each, shared by all blocks, L2-resident)
// and z are loaded DIRECTLY global->VGPR as MFMA fragments -- per-wave,
// independent, no LDS staging, no vmcnt choreography; the compiler
// pipelines them (m97 behavior). LDS remains only for the cross-wave
// transposes x1 and the x2 slab: 9 barriers total (1 after x1, 2/slab).
// Fragment mapping (verified R13-R17): lane (lm,q) of wave -> A[row][k]
// with row=base+lm, k=c*32+q*8; af/bf = contiguous half8 at that address.
// LDS 48 KB: X1 [8 ch][64 r][32] swizzled (32 KB) + SLAB [4 ch][64 r][32]
// (16 KB). Swizzle: element (row,col) -> chunk col>>5, half
// ((col&31)>>3 ^ ((row>>2)&3))*8 + (col&7); read side csw matches.
__global__ __launch_bounds__(512, 4) void fused_mlp(
    const ushort* __restrict__ z16, const ushort* __restrict__ W1T,
    const float* __restrict__ b1, const ushort* __restrict__ W2T,
    const float* __restrict__ b2, const ushort* __restrict__ WgT,
    const float* __restrict__ attS, const float* __restrict__ attD,
    float* __restrict__ aS, float* __restrict__ aD,
    unsigned char* __restrict__ xp8, int M)
{
    __shared__ ushort lds[24576];   // 48 KB

    const int t = threadIdx.x;
    const int l = t & 63;
    const int w = t >> 6;                 // 0..7
    const int wr = w & 3;                 // row group (16 rows)
    const int wc = w >> 2;                // col half
    const int lm = l & 15;
    const int q  = l >> 4;
    const int q4 = q * 4;
    const int row0 = (int)blockIdx.x * 64;
    const int csw = ((q ^ ((lm >> 2) & 3)) << 3);        // frag-read swz

    constexpr int X1   = 0;
    constexpr int SLAB = 16384;
    const f32x4 zf = {0.f, 0.f, 0.f, 0.f};

    // ================= P1: x1 = relu(z @ W1 + b1), K=512 =================
    f32x4 acc1[8];
    #pragma unroll
    for (int i = 0; i < 8; ++i) acc1[i] = zf;
    {
        const ushort* ar = z16 + (size_t)(row0 + wr * 16 + lm) * 512 + q * 8;
        const ushort* br = W1T + (size_t)(wc * 128 + lm) * 512 + q * 8;
        #pragma unroll
        for (int c = 0; c < 16; ++c) {
            half8 af = *(const half8*)(ar + c * 32);
            #pragma unroll
            for (int ni = 0; ni < 8; ++ni) {
                half8 bf = *(const half8*)(br + (size_t)(ni * 16) * 512 + c * 32);
                acc1[ni] = __builtin_amdgcn_mfma_f32_16x16x32_f16(af, bf, acc1[ni], 0, 0, 0);
            }
        }
    }
    #pragma unroll
    for (int ni = 0; ni < 8; ++ni) {      // x1 -> X1 (swizzled)
        const int col = wc * 128 + ni * 16 + lm;
        const float bv = b1[col];
        const int ch = col >> 5, c5 = col & 31;
        #pragma unroll
        for (int r = 0; r < 4; ++r) {
            const int row = wr * 16 + q4 + r;
            const float v = fmaxf(acc1[ni][r] + bv, 0.f);
            lds[X1 + ch * 2048 + row * 32 + (((c5 >> 3) ^ q) << 3) + (c5 & 7)] = f2h(v);
        }
    }
    asm volatile("s_waitcnt lgkmcnt(0)" ::: "memory");
    __builtin_amdgcn_s_barrier();
    __builtin_amdgcn_sched_barrier(0);

    // ========== slab loop: P2(s) x2-slab -> P3(s) acc3 += slab@Wg ==========
    f32x4 acc3[8];
    #pragma unroll
    for (int i = 0; i < 8; ++i) acc3[i] = zf;

    #pragma unroll
    for (int s = 0; s < 4; ++s) {
        // ---- P2(s): slab = relu(x1 @ W2[:, s*128..+128] + b2), K=256 ----
        f32x4 acc2[4];
        #pragma unroll
        for (int i = 0; i < 4; ++i) acc2[i] = zf;
        {
            const ushort* br = W2T + (size_t)(s * 128 + wc * 64 + lm) * 256 + q * 8;
            #pragma unroll
            for (int c = 0; c < 8; ++c) {
                half8 af = *(const half8*)&lds[X1 + c * 2048 + (wr * 16 + lm) * 32 + csw];
                #pragma unroll
                for (int ni = 0; ni < 4; ++ni) {
                    half8 bf = *(const half8*)(br + (size_t)(ni * 16) * 256 + c * 32);
                    acc2[ni] = __builtin_amdgcn_mfma_f32_16x16x32_f16(af, bf, acc2[ni], 0, 0, 0);
                }
            }
        }
        __builtin_amdgcn_s_barrier();     // all P3(s-1) SLAB reads done
        __builtin_amdgcn_sched_barrier(0);
        #pragma unroll
        for (int ni = 0; ni < 4; ++ni) {  // slab -> SLAB (swizzled)
            const int c7 = wc * 64 + ni * 16 + lm;
            const float bv = b2[s * 128 + c7];
            const int ch = c7 >> 5, c5 = c7 & 31;
            #pragma unroll
            for (int r = 0; r < 4; ++r) {
                const int row = wr * 16 + q4 + r;
                const float v = fmaxf(acc2[ni][r] + bv, 0.f);
                lds[SLAB + ch * 2048 + row * 32 + (((c5 >> 3) ^ q) << 3) + (c5 & 7)] = f2h(v);
            }
        }
        asm volatile("s_waitcnt lgkmcnt(0)" ::: "memory");
        __builtin_amdgcn_s_barrier();
        __builtin_amdgcn_sched_barrier(0);

        // ---- P3(s): acc3 += slab @ Wg[s*128..+128, :], K=128 ----
        {
            const ushort* br = WgT + (size_t)(wc * 128 + lm) * 512 + s * 128 + q * 8;
            #pragma unroll
            for (int c = 0; c < 4; ++c) {
                half8 af = *(const half8*)&lds[SLAB + c * 2048 + (wr * 16 + lm) * 32 + csw];
                #pragma unroll
                for (int ni = 0; ni < 8; ++ni) {
                    half8 bf = *(const half8*)(br + (size_t)(ni * 16) * 512 + c * 32);
                    acc3[ni] = __builtin_amdgcn_mfma_f32_16x16x32_f16(af, bf, acc3[ni], 0, 0, 0);
                }
            }
        }
    }

    // ============ epilogue: xp8 = fp8(acc3) + att logits ============
    const int h = wc;
    float asv[8], adv[8];
    #pragma unroll
    for (int ni = 0; ni < 8; ++ni) {
        const int col = wc * 128 + ni * 16 + lm;
        asv[ni] = attS[col];
        adv[ni] = attD[col];
    }
    #pragma unroll
    for (int r = 0; r < 4; ++r) {
        const int row = row0 + wr * 16 + q4 + r;
        float ps = 0.f, pd = 0.f;
        #pragma unroll
        for (int ni = 0; ni < 8; ++ni) {
            const float v = acc3[ni][r];
            ps += v * asv[ni];
            pd += v * adv[ni];
            if (row < M)
                xp8[(size_t)row * HC + wc * 128 + ni * 16 + lm] =
                    (unsigned char)f32_to_e4m3(v);
        }
        #pragma unroll
        for (int off = 8; off > 0; off >>= 1) {
            ps += __shfl_xor(ps, off);
            pd += __shfl_xor(pd, off);
        }
        if (lm == 0 && row < M) {
            atomicAdd(&aS[2 * row + h], ps);
            atomicAdd(&aD[2 * row + h], pd);
        }
    }
}

// ---------------------------------------------------------------------------
// R18: GEMM4 direct -- no LDS, no barriers. xg rows and W3T stream from
// L2 straight into fragments (W3T 256 KB shared chip-wide; xg per-XCD
// working set ~1.3 MB under the bijective remap). Block = 128x64, 4 waves
// (wave 64x32), 1256 blocks. out = xg @ W3 + b3 -> fp32.
__global__ __launch_bounds__(256, 4) void gemm4_direct(
    const ushort* __restrict__ A,   // xg [M+128, 256] f16
    const ushort* __restrict__ BT,  // W3T [512, 256] f16
    const float* __restrict__ bias,
    float* __restrict__ C, int M)
{
    const int t = threadIdx.x;
    const int l = t & 63;
    const int w = t >> 6;
    const int wm = (w >> 1) * 64;
    const int wn = (w & 1) * 32;
    const int lm = l & 15;
    const int q  = l >> 4;
    const int q4 = q * 4;

    // XCD-aware bijective block remap (R15), nby=8 (512/64)
    const int T  = (int)gridDim.x;
    const int qq = T >> 3, rr = T & 7;
    const int kx = (int)blockIdx.x & 7;
    const int jx = (int)blockIdx.x >> 3;
    const int lin = kx * qq + (kx < rr ? kx : rr) + jx;
    const int row0 = (lin >> 3) * 128;
    const int col0 = (lin & 7) * 64;

    const f32x4 zf = {0.f, 0.f, 0.f, 0.f};
    f32x4 acc[4][2];
    #pragma unroll
    for (int i = 0; i < 4; ++i) { acc[i][0] = zf; acc[i][1] = zf; }

    const ushort* ar = A + (size_t)(row0 + wm + lm) * 256 + q * 8;
    const ushort* br = BT + (size_t)(col0 + wn + lm) * 256 + q * 8;

    #pragma unroll
    for (int c = 0; c < 8; ++c) {
        half8 bf0 = *(const half8*)(br + c * 32);
        half8 bf1 = *(const half8*)(br + (size_t)16 * 256 + c * 32);
        #pragma unroll
        for (int mi = 0; mi < 4; ++mi) {
            half8 af = *(const half8*)(ar + (size_t)(mi * 16) * 256 + c * 32);
            acc[mi][0] = __builtin_amdgcn_mfma_f32_16x16x32_f16(af, bf0, acc[mi][0], 0, 0, 0);
            acc[mi][1] = __builtin_amdgcn_mfma_f32_16x16x32_f16(af, bf1, acc[mi][1], 0, 0, 0);
        }
    }

    #pragma unroll
    for (int mi = 0; mi < 4; ++mi) {
        #pragma unroll
        for (int ni = 0; ni < 2; ++ni) {
            const int col = col0 + wn + ni * 16 + lm;
            const float bv = bias[col];
            #pragma unroll
            for (int r = 0; r < 4; ++r) {
                const int row = row0 + wm + mi * 16 + q4 + r;
                if (row >= M) continue;
                C[(size_t)row * 512 + col] = acc[mi][ni][r] + bv;
            }
        }
    }
}

// ---------------------------------------------------------------------------
// Fused prologue, one launch:
//   blocks [0,10000):      z fp32 -> f16 (x4) + deg/cursor/a_src/a_dst zero
//   blocks [10000,12048):  4 weight transposes W[K,N] fp32 -> WT[N,K] f16
#define CVT_BLOCKS 10000
#define TR_BLOCKS  2048
__global__ __launch_bounds__(256) void prologue_kernel(
    const float* __restrict__ z, ushort* __restrict__ z_f16,
    int* deg, int* cursor, float* aS, float* aD, int n,
    const float* __restrict__ W1, const float* __restrict__ W2,
    const float* __restrict__ Wg, const float* __restrict__ W3,
    ushort* __restrict__ T1, ushort* __restrict__ T2,
    ushort* __restrict__ Tg, ushort* __restrict__ T3)
{
    const int b = blockIdx.x;
    if (b < CVT_BLOCKS) {
        int i = b * 256 + threadIdx.x;
        if (i < n) {
            deg[i] = 0; cursor[i] = 0;
            ((float2*)aS)[i] = make_float2(0.f, 0.f);
            ((float2*)aD)[i] = make_float2(0.f, 0.f);
        }
        float4 v = ((const float4*)z)[i];
        ((ushort4*)z_f16)[i] = make_ushort4(f2h(v.x), f2h(v.y), f2h(v.z), f2h(v.w));
    } else {
        int idx = (b - CVT_BLOCKS) * 256 + threadIdx.x;
        int which = idx >> 17, i = idx & 131071;
        const float* W; ushort* T; int K, N;
        if (which == 0)      { W = W1; T = T1; K = 512; N = 256; }
        else if (which == 1) { W = W2; T = T2; K = 256; N = 512; }
        else if (which == 2) { W = Wg; T = Tg; K = 512; N = 256; }
        else                 { W = W3; T = T3; K = 256; N = 512; }
        int k = i / N, nn = i - k * N;
        T[(size_t)nn * K + k] = f2h(W[i]);
    }
}

// ---------------------------------------------------------------------------
__global__ __launch_bounds__(256) void hist_kernel(
    const int* __restrict__ dst, int* deg, int E_real, int ET)
{
    int e = blockIdx.x * blockDim.x + threadIdx.x;
    if (e >= ET) return;
    int d = (e < E_real) ? dst[e] : (e - E_real);
    atomicAdd(&deg[d], 1);
}

// Exclusive scan deg[0..n) -> rowptr[0..n]; single block, 1024 threads.
__global__ __launch_bounds__(1024) void scan_kernel(
    const int* __restrict__ deg, int* __restrict__ rowptr, int n)
{
    __shared__ int part[1024];
    const int t = threadIdx.x;
    const int chunk = (n + 1023) / 1024;
    const int lo = t * chunk;
    const int hi = min(lo + chunk, n);
    int s = 0;
    for (int i = lo; i < hi; ++i) s += deg[i];
    part[t] = s;
    __syncthreads();
    #pragma unroll
    for (int off = 1; off < 1024; off <<= 1) {
        int add = (t >= off) ? part[t - off] : 0;
        __syncthreads();
        part[t] += add;
        __syncthreads();
    }
    int run = part[t] - s;   // exclusive prefix of this thread's chunk
    for (int i = lo; i < hi; ++i) { rowptr[i] = run; run += deg[i]; }
    if (t == 1023) rowptr[n] = part[1023];
}

__global__ __launch_bounds__(256) void scatter_kernel(
    const int* __restrict__ src, const int* __restrict__ dst,
    const int* __restrict__ rowptr, int* cursor,
    int* __restrict__ sorted_src, int E_real, int ET)
{
    int e = blockIdx.x * blockDim.x + threadIdx.x;
    if (e >= ET) return;
    int s, d;
    if (e < E_real) { s = src[e]; d = dst[e]; }
    else            { s = e - E_real; d = s; }
    int pos = rowptr[d] + atomicAdd(&cursor[d], 1);
    sorted_src[pos] = s;
}

// ---------------------------------------------------------------------------
// 4 waves/block, ONE node per wave. Single pass (no segment-max: logits
// |a|<~0.05, exp(a)/sum == exp(a-max)/sum), no LDS, no barriers; weights
// packed so ONE shfl serves both heads; unroll x8 = 8 gathers in flight.
// xp is fp8 e4m3 -> 256 B/edge row (R14; fetch-BW bound fix).
__global__ __launch_bounds__(256) void gat_aggregate(
    const int* __restrict__ rowptr, const int* __restrict__ sorted_src,
    const float* __restrict__ a_src, const float* __restrict__ a_dst,
    const unsigned char* __restrict__ xp8, const float* __restrict__ bias_g,
    ushort* __restrict__ xg, int n)
{
    const int d = blockIdx.x * 4 + (threadIdx.x >> 6);
    if (d >= n) return;
    const int lane = threadIdx.x & 63;
    const int hsel = lane & 32;
    const int start = rowptr[d], end = rowptr[d + 1];

    const float ad0 = a_dst[2 * d + 0];
    const float ad1 = a_dst[2 * d + 1];

    float4 acc = make_float4(0.f, 0.f, 0.f, 0.f);
    float denom = 0.f;

    for (int e0 = start; e0 < end; e0 += 32) {
        const int cnt = min(32, end - e0);
        const int idx = lane & 31;
        float wsel = 0.f; int off = 0;
        if (idx < cnt) {
            int s = sorted_src[e0 + idx];
            float v0 = a_src[2 * s + 0] + ad0;
            float v1 = a_src[2 * s + 1] + ad1;
            v0 = (v0 > 0.f) ? v0 : NEG_SLOPE * v0;
            v1 = (v1 > 0.f) ? v1 : NEG_SLOPE * v1;
            wsel = (lane < 32) ? __expf(v0) : __expf(v1);
            off = s * HC;
        }
        int j = 0;
        for (; j + 8 <= cnt; j += 8) {
            float w_[8]; int o_[8];
            #pragma unroll
            for (int u = 0; u < 8; ++u) {
                w_[u] = __shfl(wsel, (j + u) + hsel);
                o_[u] = __shfl(off, j + u);
            }
            uint v_[8];
            #pragma unroll
            for (int u = 0; u < 8; ++u)
                v_[u] = *(const uint*)(xp8 + o_[u] + 4 * lane);
            #pragma unroll
            for (int u = 0; u < 8; ++u) {
                denom += w_[u];
#if FP8_HW
                f32x2 lo = __builtin_amdgcn_cvt_pk_f32_fp8((int)v_[u], false);
                f32x2 hi = __builtin_amdgcn_cvt_pk_f32_fp8((int)v_[u], true);
                acc.x += w_[u] * lo.x; acc.y += w_[u] * lo.y;
                acc.z += w_[u] * hi.x; acc.w += w_[u] * hi.y;
#else
                const float wu = w_[u] * 256.0f;
                const uint b = v_[u];
                acc.x += wu * h2f(((b & 0x80u) << 8) | ((b & 0x7fu) << 7));
                acc.y += wu * h2f((((b >> 8) & 0x80u) << 8) | (((b >> 8) & 0x7fu) << 7));
                acc.z += wu * h2f((((b >> 16) & 0x80u) << 8) | (((b >> 16) & 0x7fu) << 7));
                acc.w += wu * h2f((((b >> 24) & 0x80u) << 8) | (((b >> 24) & 0x7fu) << 7));
#endif
            }
        }
        for (; j < cnt; ++j) {
            const float w = __shfl(wsel, j + hsel);
            const int   o = __shfl(off, j);
            const uint  b = *(const uint*)(xp8 + o + 4 * lane);
            denom += w;
#if FP8_HW
            f32x2 lo = __builtin_amdgcn_cvt_pk_f32_fp8((int)b, false);
            f32x2 hi = __builtin_amdgcn_cvt_pk_f32_fp8((int)b, true);
            acc.x += w * lo.x; acc.y += w * lo.y;
            acc.z += w * hi.x; acc.w += w * hi.y;
#else
            const float wu = w * 256.0f;
            acc.x += wu * h2f(((b & 0x80u) << 8) | ((b & 0x7fu) << 7));
            acc.y += wu * h2f((((b >> 8) & 0x80u) << 8) | (((b >> 8) & 0x7fu) << 7));
            acc.z += wu * h2f((((b >> 16) & 0x80u) << 8) | (((b >> 16) & 0x7fu) << 7));
            acc.w += wu * h2f((((b >> 24) & 0x80u) << 8) | (((b >> 24) & 0x7fu) << 7));
#endif
        }
    }

    const float inv = 1.f / fmaxf(denom, 1e-16f);
    const int c = 4 * lane;
    const float4 bg = *(const float4*)(bias_g + c);
    const size_t base = ((size_t)d * HC + c) >> 2;
    ((ushort4*)xg)[base] = make_ushort4(
        f2h(acc.x * inv + bg.x), f2h(acc.y * inv + bg.y),
        f2h(acc.z * inv + bg.z), f2h(acc.w * inv + bg.w));
}

// ---------------------------------------------------------------------------
extern "C" void kernel_launch(void* const* d_in, const int* in_sizes, int n_in,
                              void* d_out, int out_size, void* d_ws, size_t ws_size,
                              hipStream_t stream)
{
    const float* z       = (const float*)d_in[0];
    const int*   ei      = (const int*)d_in[1];    // [2,E] int32
    const float* W1      = (const float*)d_in[2];
    const float* b1      = (const float*)d_in[3];
    const float* W2      = (const float*)d_in[4];
    const float* b2      = (const float*)d_in[5];
    const float* Wg      = (const float*)d_in[6];
    const float* att_src = (const float*)d_in[7];
    const float* att_dst = (const float*)d_in[8];
    const float* bias_g  = (const float*)d_in[9];
    const float* W3      = (const float*)d_in[10];
    const float* b3      = (const float*)d_in[11];
    float* out = (float*)d_out;

    const int n = N_NODES;
    const int E_real = in_sizes[1] / 2;
    const int ET = E_real + n;
    const int* src = ei;
    const int* dst = ei + E_real;

    char* p = (char*)d_ws;
    auto alloc = [&](size_t bytes) {
        char* r = p;
        p += (bytes + 63) & ~(size_t)63;
        return r;
    };
    const int np = n + 128;
    ushort* z_f16  = (ushort*)alloc((size_t)np * LATENT * 2);  // 20.6 MB
    ushort* xg_f16 = (ushort*)alloc((size_t)np * HID * 2);     // 10.3 MB
    unsigned char* xp8 = (unsigned char*)alloc((size_t)n * HC); // 5.1 MB
    ushort* W1T = (ushort*)alloc((size_t)LATENT * HID * 2);
    ushort* W2T = (ushort*)alloc((size_t)HID * 512 * 2);
    ushort* WgT = (ushort*)alloc((size_t)512 * HC * 2);
    ushort* W3T = (ushort*)alloc((size_t)HC * 512 * 2);
    float* a_src = (float*)alloc((size_t)2 * n * 4);
    float* a_dst = (float*)alloc((size_t)2 * n * 4);
    int* deg        = (int*)alloc((size_t)n * 4);
    int* rowptr     = (int*)alloc(((size_t)n + 1) * 4);
    int* cursor     = (int*)alloc((size_t)n * 4);
    int* sorted_src = (int*)alloc((size_t)ET * 4);

    const int gm128 = (n + 127) / 128;   // 157

    // prologue: z->f16 + deg/cursor/a_src/a_dst zero + 4 weight transposes
    prologue_kernel<<<CVT_BLOCKS + TR_BLOCKS, 256, 0, stream>>>(
        z, z_f16, deg, cursor, a_src, a_dst, n,
        W1, W2, Wg, W3, W1T, W2T, WgT, W3T);
    // CSR build (independent of the MLP chain until gat)
    hist_kernel<<<(ET + 255) / 256, 256, 0, stream>>>(dst, deg, E_real, ET);
    scan_kernel<<<1, 1024, 0, stream>>>(deg, rowptr, n);
    scatter_kernel<<<(ET + 255) / 256, 256, 0, stream>>>(
        src, dst, rowptr, cursor, sorted_src, E_real, ET);

    // FUSED MLP v3 (48 KB LDS, 9 barriers, operands direct from L2):
    // x1/x2-slabs in LDS; xp8 + attention logits out
    fused_mlp<<<(n + 63) / 64, 512, 0, stream>>>(
        z_f16, W1T, b1, W2T, b2, WgT,
        att_src, att_dst, a_src, a_dst, xp8, n);

    // softmax + aggregate -> xg (f16): 4 nodes per block, one wave each
    gat_aggregate<<<(n + 3) / 4, 256, 0, stream>>>(
        rowptr, sorted_src, a_src, a_dst, xp8, bias_g, xg_f16, n);

    // GEMM4 direct (no LDS, no barriers): out = xg @ W3 + b3, 1256 blocks
    gemm4_direct<<<gm128 * 8, 256, 0, stream>>>(
        xg_f16, W3T, b3, out, n);
}

// Round 9
// 297.596 us; speedup vs baseline: 1.4888x; 1.4888x over previous
//
#include <hip/hip_runtime.h>
#include <hip/hip_bf16.h>
#include <float.h>

// Problem constants (from reference)
#define N_NODES 20000
#define LATENT  512
#define HID     256
#define OUT_C   128
#define HEADS   2
#define HC      256   // HEADS*OUT_C
#define NEG_SLOPE 0.2f

typedef _Float16 half8 __attribute__((ext_vector_type(8)));  // 8 f16 = 4 VGPRs
typedef __attribute__((ext_vector_type(4))) float f32x4;
typedef __attribute__((ext_vector_type(2))) float f32x2;

// ---------------------------------------------------------------------------
__device__ __forceinline__ ushort f2h(float v) {
    _Float16 h = (_Float16)v;
    return *(ushort*)&h;
}
__device__ __forceinline__ float h2f(ushort u) {
    _Float16 h = *(_Float16*)&u;
    return (float)h;
}

// ---- fp8 e4m3 (OCP) encode/decode. Prefer HW cvt; exact bit-trick fallback.
#if __has_builtin(__builtin_amdgcn_cvt_pk_fp8_f32) && __has_builtin(__builtin_amdgcn_cvt_pk_f32_fp8)
#define FP8_HW 1
#else
#define FP8_HW 0
#endif

__device__ __forceinline__ uint f32_to_e4m3(float v) {
#if FP8_HW
    return (uint)(__builtin_amdgcn_cvt_pk_fp8_f32(v, v, 0, false) & 0xff);
#else
    _Float16 hf = (_Float16)(v * 0.00390625f);   // *2^-8
    uint hb = *(ushort*)&hf;
    uint s = (hb >> 8) & 0x80;
    uint mag = hb & 0x7fff;
    mag = (mag + 0x3f + ((mag >> 7) & 1)) >> 7;  // RNE 10->3 mantissa bits
    if (mag > 0x7e) mag = 0x7e;
    return s | mag;
#endif
}

// async global->LDS DMA, 16B per lane. LDS dest is WAVE-UNIFORM base +
// lane*16 (m104/m108); per-lane scatter impossible -> XOR chunk swizzle.
__device__ __forceinline__ void gl_lds16(const ushort* g, ushort* l) {
    __builtin_amdgcn_global_load_lds(
        (const __attribute__((address_space(1))) unsigned int*)g,
        (__attribute__((address_space(3))) unsigned int*)l, 16, 0, 0);
}

// ---------------------------------------------------------------------------
// R19: fused MLP v4 = R17's STAGED pipeline (R18's direct-from-L2 fragment
// loads were 64-lines-per-load uncoalesced, 44->185 us -- reverted) with
// 32-ROW BLOCKS: 625 blocks (~2.4/CU) at 72 KB LDS (2 blocks/CU resident)
// so one block's DMA-wait+barrier segments hide under the other's MFMAs.
// Block = 512 thr / 8 waves; wave tile 16 rows: wr=w&1 row group,
// wc=w>>1 col quarter (64 cols in P1/P3, 32 in P2).
// LDS map (halfs): X1 [0,8192) x1 32x256 as [8 ch][32 r][32] XOR-swz;
// SLAB [8192,12288) x2 slab 32x128 [4 ch][32 r][32]; SB [12288,28672)
// P3 staging 2x8192; P2ST [28672,36864) P2 staging 2x4096.
// P1 staging: 3 bufs x 9216 at 0/9216/18432 (aliases X1/SLAB/SB -- those
// are written only after all P1 chunks consumed). Per-chunk DMAs/wave:
// P1 3 (w<2) / 2, P2 1, P3 2 -> vmcnt immediates as in R17.
__global__ __launch_bounds__(512, 4) void fused_mlp(
    const ushort* __restrict__ z16, const ushort* __restrict__ W1T,
    const float* __restrict__ b1, const ushort* __restrict__ W2T,
    const float* __restrict__ b2, const ushort* __restrict__ WgT,
    const float* __restrict__ attS, const float* __restrict__ attD,
    float* __restrict__ aS, float* __restrict__ aD,
    unsigned char* __restrict__ xp8, int M)
{
    __shared__ ushort lds[36864];   // 72 KB -> 2 blocks/CU

    const int t = threadIdx.x;
    const int l = t & 63;
    const int w = t >> 6;                 // 0..7
    const int wr = w & 1;                 // row group (16 rows)
    const int wc = w >> 1;                // col quarter
    const int lm = l & 15;
    const int q  = l >> 4;
    const int q4 = q * 4;
    const int row0 = (int)blockIdx.x * 32;
    const int lr16 = l >> 2;              // staging row within 16
    const int gsh = (((l & 3) ^ ((l >> 4) & 3)) << 3);   // global half off
    const int csw = ((q ^ ((lm >> 2) & 3)) << 3);        // frag-read swz

    constexpr int X1   = 0;
    constexpr int SLAB = 8192;
    constexpr int SB   = 12288;
    constexpr int P2ST = 28672;

    auto barsync = [&]() {
        __builtin_amdgcn_s_barrier();
        __builtin_amdgcn_sched_barrier(0);
    };

    // ---- staging (1 KB per instr = 16 rows of a 32-K chunk) ----
    auto issue1 = [&](int c) {            // z 2 instr + W1T 16 instr
        ushort* B = &lds[(c % 3) * 9216];
        const int kk = c * 32;
        #pragma unroll
        for (int u = 0; u < 3; ++u) {
            const int ii = w + u * 8;
            if (ii < 18) {
                const ushort* g = (ii < 2)
                    ? z16 + (size_t)(row0 + ii * 16 + lr16) * 512 + kk + gsh
                    : W1T + (size_t)((ii - 2) * 16 + lr16) * 512 + kk + gsh;
                gl_lds16(g, B + ii * 512);
            }
        }
    };
    auto issue2 = [&](int s, int c) {     // W2T slab 128 rows: 8 instr (1/wave)
        ushort* B = &lds[P2ST + (c & 1) * 4096];
        gl_lds16(W2T + (size_t)(s * 128 + w * 16 + lr16) * 256 + c * 32 + gsh,
                 B + w * 512);
    };
    auto issue3 = [&](int s, int c) {     // WgT 256 rows: 16 instr (2/wave)
        ushort* B = &lds[SB + (c & 1) * 8192];
        #pragma unroll
        for (int u = 0; u < 2; ++u) {
            const int ii = w + u * 8;
            gl_lds16(WgT + (size_t)(ii * 16 + lr16) * 512 + s * 128 + c * 32 + gsh,
                     B + ii * 512);
        }
    };

    const f32x4 zf = {0.f, 0.f, 0.f, 0.f};

    // ================= phase 1: x1 = relu(z @ W1 + b1), K=512 =================
    f32x4 acc1[4];
    #pragma unroll
    for (int i = 0; i < 4; ++i) acc1[i] = zf;

    issue1(0); issue1(1);                 // 3-buf, depth-2
    for (int c = 0; c < 16; ++c) {
        __builtin_amdgcn_sched_barrier(0);
        if (c + 1 < 16) {
            if (w < 2) asm volatile("s_waitcnt vmcnt(3)" ::: "memory");
            else       asm volatile("s_waitcnt vmcnt(2)" ::: "memory");
        } else         asm volatile("s_waitcnt vmcnt(0)" ::: "memory");
        barsync();
        if (c + 2 < 16) issue1(c + 2);
        const ushort* B = &lds[(c % 3) * 9216];
        half8 af = *(const half8*)&B[(wr * 16 + lm) * 32 + csw];
        #pragma unroll
        for (int ni = 0; ni < 4; ++ni) {
            half8 bf = *(const half8*)&B[1024 + (wc * 64 + ni * 16 + lm) * 32 + csw];
            acc1[ni] = __builtin_amdgcn_mfma_f32_16x16x32_f16(af, bf, acc1[ni], 0, 0, 0);
        }
    }
    __builtin_amdgcn_s_barrier();         // all waves done reading P1 bufs
    issue2(0, 0); issue2(0, 1);           // prefetch P2(0) (P2ST disjoint)
    #pragma unroll
    for (int ni = 0; ni < 4; ++ni) {      // x1 -> X1 (swizzled for A-reads)
        const int col = wc * 64 + ni * 16 + lm;
        const float bv = b1[col];
        const int ch = col >> 5, c5 = col & 31;
        #pragma unroll
        for (int r = 0; r < 4; ++r) {
            const int row = wr * 16 + q4 + r;
            const float v = fmaxf(acc1[ni][r] + bv, 0.f);
            lds[X1 + ch * 1024 + row * 32 + (((c5 >> 3) ^ q) << 3) + (c5 & 7)] = f2h(v);
        }
    }
    asm volatile("s_waitcnt lgkmcnt(0)" ::: "memory");
    barsync();

    // ========== slab loop: P2(s) x2-slab -> P3(s) acc3 += slab@Wg ==========
    f32x4 acc3[4];
    #pragma unroll
    for (int i = 0; i < 4; ++i) acc3[i] = zf;

    for (int s = 0; s < 4; ++s) {
        // ---- P2(s): slab = relu(x1 @ W2[:, s*128..+128] + b2), K=256 ----
        f32x4 acc2[2];
        acc2[0] = zf; acc2[1] = zf;

        for (int c = 0; c < 8; ++c) {
            __builtin_amdgcn_sched_barrier(0);
            if (c == 0) asm volatile("s_waitcnt vmcnt(1)" ::: "memory");
            else        asm volatile("s_waitcnt vmcnt(0)" ::: "memory");
            barsync();
            if (c >= 1 && c + 1 < 8) issue2(s, c + 1);   // buf consumed @ bar
            if (c == 7) { issue3(s, 0); issue3(s, 1); }  // SB bufs long dead
            const ushort* Bf = &lds[P2ST + (c & 1) * 4096];
            half8 af = *(const half8*)&lds[X1 + c * 1024 + (wr * 16 + lm) * 32 + csw];
            #pragma unroll
            for (int ni = 0; ni < 2; ++ni) {
                half8 bf = *(const half8*)&Bf[(wc * 32 + ni * 16 + lm) * 32 + csw];
                acc2[ni] = __builtin_amdgcn_mfma_f32_16x16x32_f16(af, bf, acc2[ni], 0, 0, 0);
            }
        }
        __builtin_amdgcn_s_barrier();     // all compute2(7) done
        #pragma unroll
        for (int ni = 0; ni < 2; ++ni) {  // slab -> SLAB (swizzled)
            const int c7 = wc * 32 + ni * 16 + lm;
            const float bv = b2[s * 128 + c7];
            const int ch = c7 >> 5, c5 = c7 & 31;
            #pragma unroll
            for (int r = 0; r < 4; ++r) {
                const int row = wr * 16 + q4 + r;
                const float v = fmaxf(acc2[ni][r] + bv, 0.f);
                lds[SLAB + ch * 1024 + row * 32 + (((c5 >> 3) ^ q) << 3) + (c5 & 7)] = f2h(v);
            }
        }
        asm volatile("s_waitcnt lgkmcnt(0)" ::: "memory");
        barsync();

        // ---- P3(s): acc3 += slab @ Wg[s*128..+128, :], K=128 ----
        for (int c = 0; c < 4; ++c) {
            __builtin_amdgcn_sched_barrier(0);
            if (c == 0)                asm volatile("s_waitcnt vmcnt(2)" ::: "memory");
            else if (c == 3 && s < 3)  asm volatile("s_waitcnt vmcnt(1)" ::: "memory");
            else                       asm volatile("s_waitcnt vmcnt(0)" ::: "memory");
            barsync();
            if (c == 1) issue3(s, 2);                    // buf0 consumed @ bar
            if (c == 2) { issue3(s, 3);                  // buf1 consumed @ bar
                          if (s < 3) issue2(s + 1, 0); } // P2ST buf0 long dead
            const ushort* Bf = &lds[SB + (c & 1) * 8192];
            half8 af = *(const half8*)&lds[SLAB + c * 1024 + (wr * 16 + lm) * 32 + csw];
            #pragma unroll
            for (int ni = 0; ni < 4; ++ni) {
                half8 bf = *(const half8*)&Bf[(wc * 64 + ni * 16 + lm) * 32 + csw];
                acc3[ni] = __builtin_amdgcn_mfma_f32_16x16x32_f16(af, bf, acc3[ni], 0, 0, 0);
            }
        }
        __builtin_amdgcn_s_barrier();     // all compute3(3) done (SLAB free)
        if (s < 3) issue2(s + 1, 1);
        __builtin_amdgcn_sched_barrier(0);
    }

    // ============ epilogue: xp8 = fp8(acc3) + att logits ============
    const int h = wc >> 1;                // cols wc*64..+63 lie in one head
    float asv[4], adv[4];
    #pragma unroll
    for (int ni = 0; ni < 4; ++ni) {
        const int col = wc * 64 + ni * 16 + lm;
        asv[ni] = attS[col];
        adv[ni] = attD[col];
    }
    #pragma unroll
    for (int r = 0; r < 4; ++r) {
        const int row = row0 + wr * 16 + q4 + r;
        float ps = 0.f, pd = 0.f;
        #pragma unroll
        for (int ni = 0; ni < 4; ++ni) {
            const float v = acc3[ni][r];
            ps += v * asv[ni];
            pd += v * adv[ni];
            if (row < M)
                xp8[(size_t)row * HC + wc * 64 + ni * 16 + lm] =
                    (unsigned char)f32_to_e4m3(v);
        }
        #pragma unroll
        for (int off = 8; off > 0; off >>= 1) {
            ps += __shfl_xor(ps, off);
            pd += __shfl_xor(pd, off);
        }
        if (lm == 0 && row < M) {
            atomicAdd(&aS[2 * row + h], ps);
            atomicAdd(&aD[2 * row + h], pd);
        }
    }
}

// ---------------------------------------------------------------------------
// fp16 MFMA GEMM (GEMM4 only; R15-proven). Block tile 128x64, 4 waves,
// BK=32, 3-buffer counted-vmcnt pipeline, XCD-aware bijective swizzle.
template<int BN, int LOGNBY>
__global__ __launch_bounds__(256, 4) void gemm_f16(
    const ushort* __restrict__ A, const ushort* __restrict__ BT,
    const float* __restrict__ bias,
    float* __restrict__ Cf, ushort* __restrict__ Ch,
    int M, int N, int K, int relu)
{
    static_assert(BN == 64, "vmcnt immediates assume 3 DMAs/chunk");
    constexpr int NI  = BN / 32;
    constexpr int BUF = 4096 + BN * 32;
    __shared__ ushort lds[3 * BUF];

    const int t = threadIdx.x;
    const int l = t & 63;
    const int w = t >> 6;
    const int wm = (w >> 1) * 64;
    const int wn = (w & 1) * (BN / 2);
    const int lm = l & 15;
    const int q  = l >> 4;
    const int q4 = q * 4;

    const int T  = (int)gridDim.x;
    const int qq = T >> 3, rr = T & 7;
    const int kx = (int)blockIdx.x & 7;
    const int jx = (int)blockIdx.x >> 3;
    const int lin = kx * qq + (kx < rr ? kx : rr) + jx;
    const int row0 = (lin >> LOGNBY) * 128;
    const int col0 = (lin & ((1 << LOGNBY) - 1)) * BN;

    const int jr0 = w * 16 + (l >> 2);
    const int gsh = (((l & 3) ^ ((l >> 4) & 3)) << 3);
    const ushort* gA0 = A + (size_t)(row0 + jr0) * K + gsh;
    const ushort* gA1 = gA0 + (size_t)64 * K;
    const ushort* gB0 = BT + (size_t)(col0 + jr0) * K + gsh;
    const int dA0 = w * 512, dA1 = (4 + w) * 512;
    const int dB0 = 4096 + w * 512;

    const int csw = ((q ^ ((lm >> 2) & 3)) << 3);

    const f32x4 zf = {0.f, 0.f, 0.f, 0.f};
    f32x4 acc[4][NI];
    #pragma unroll
    for (int i = 0; i < 4; ++i)
        #pragma unroll
        for (int j = 0; j < NI; ++j) acc[i][j] = zf;

    const int NC = K >> 5;

    auto issue = [&](int c) {
        ushort* B = lds + (size_t)(c % 3) * BUF;
        const int kk = c * 32;
        gl_lds16(gA0 + kk, B + dA0);
        gl_lds16(gA1 + kk, B + dA1);
        gl_lds16(gB0 + kk, B + dB0);
    };

    auto compute = [&](int c) {
        const ushort* B = lds + (size_t)(c % 3) * BUF;
        half8 bf[NI];
        #pragma unroll
        for (int ni = 0; ni < NI; ++ni) {
            const int boff = (wn + ni * 16 + lm) * 32 + csw;
            bf[ni] = *(const half8*)&B[4096 + boff];
        }
        #pragma unroll
        for (int mi = 0; mi < 4; ++mi) {
            const int aoff = (wm + mi * 16 + lm) * 32 + csw;
            half8 af = *(const half8*)&B[aoff];
            #pragma unroll
            for (int ni = 0; ni < NI; ++ni)
                acc[mi][ni] = __builtin_amdgcn_mfma_f32_16x16x32_f16(
                    af, bf[ni], acc[mi][ni], 0, 0, 0);
        }
    };

    issue(0); issue(1);
    for (int c = 0; c < NC; ++c) {
        __builtin_amdgcn_sched_barrier(0);
        if (c + 1 < NC) asm volatile("s_waitcnt vmcnt(3)" ::: "memory");
        else            asm volatile("s_waitcnt vmcnt(0)" ::: "memory");
        __builtin_amdgcn_s_barrier();
        __builtin_amdgcn_sched_barrier(0);
        if (c + 2 < NC) issue(c + 2);
        compute(c);
    }

    #pragma unroll
    for (int mi = 0; mi < 4; ++mi) {
        #pragma unroll
        for (int ni = 0; ni < NI; ++ni) {
            const int col = col0 + wn + ni * 16 + lm;
            const float bv = bias ? bias[col] : 0.f;
            #pragma unroll
            for (int r = 0; r < 4; ++r) {
                const int row = row0 + wm + mi * 16 + q4 + r;
                if (row >= M) continue;
                float v = acc[mi][ni][r] + bv;
                if (relu) v = fmaxf(v, 0.f);
                const size_t idx = (size_t)row * N + col;
                if (Cf) Cf[idx] = v;
                if (Ch) Ch[idx] = f2h(v);
            }
        }
    }
}

// ---------------------------------------------------------------------------
// Fused prologue, one launch:
//   blocks [0,10000):      z fp32 -> f16 (x4) + deg/cursor/a_src/a_dst zero
//   blocks [10000,12048):  4 weight transposes W[K,N] fp32 -> WT[N,K] f16
#define CVT_BLOCKS 10000
#define TR_BLOCKS  2048
__global__ __launch_bounds__(256) void prologue_kernel(
    const float* __restrict__ z, ushort* __restrict__ z_f16,
    int* deg, int* cursor, float* aS, float* aD, int n,
    const float* __restrict__ W1, const float* __restrict__ W2,
    const float* __restrict__ Wg, const float* __restrict__ W3,
    ushort* __restrict__ T1, ushort* __restrict__ T2,
    ushort* __restrict__ Tg, ushort* __restrict__ T3)
{
    const int b = blockIdx.x;
    if (b < CVT_BLOCKS) {
        int i = b * 256 + threadIdx.x;
        if (i < n) {
            deg[i] = 0; cursor[i] = 0;
            ((float2*)aS)[i] = make_float2(0.f, 0.f);
            ((float2*)aD)[i] = make_float2(0.f, 0.f);
        }
        float4 v = ((const float4*)z)[i];
        ((ushort4*)z_f16)[i] = make_ushort4(f2h(v.x), f2h(v.y), f2h(v.z), f2h(v.w));
    } else {
        int idx = (b - CVT_BLOCKS) * 256 + threadIdx.x;
        int which = idx >> 17, i = idx & 131071;
        const float* W; ushort* T; int K, N;
        if (which == 0)      { W = W1; T = T1; K = 512; N = 256; }
        else if (which == 1) { W = W2; T = T2; K = 256; N = 512; }
        else if (which == 2) { W = Wg; T = Tg; K = 512; N = 256; }
        else                 { W = W3; T = T3; K = 256; N = 512; }
        int k = i / N, nn = i - k * N;
        T[(size_t)nn * K + k] = f2h(W[i]);
    }
}

// ---------------------------------------------------------------------------
__global__ __launch_bounds__(256) void hist_kernel(
    const int* __restrict__ dst, int* deg, int E_real, int ET)
{
    int e = blockIdx.x * blockDim.x + threadIdx.x;
    if (e >= ET) return;
    int d = (e < E_real) ? dst[e] : (e - E_real);
    atomicAdd(&deg[d], 1);
}

// Exclusive scan deg[0..n) -> rowptr[0..n]; single block, 1024 threads.
__global__ __launch_bounds__(1024) void scan_kernel(
    const int* __restrict__ deg, int* __restrict__ rowptr, int n)
{
    __shared__ int part[1024];
    const int t = threadIdx.x;
    const int chunk = (n + 1023) / 1024;
    const int lo = t * chunk;
    const int hi = min(lo + chunk, n);
    int s = 0;
    for (int i = lo; i < hi; ++i) s += deg[i];
    part[t] = s;
    __syncthreads();
    #pragma unroll
    for (int off = 1; off < 1024; off <<= 1) {
        int add = (t >= off) ? part[t - off] : 0;
        __syncthreads();
        part[t] += add;
        __syncthreads();
    }
    int run = part[t] - s;   // exclusive prefix of this thread's chunk
    for (int i = lo; i < hi; ++i) { rowptr[i] = run; run += deg[i]; }
    if (t == 1023) rowptr[n] = part[1023];
}

__global__ __launch_bounds__(256) void scatter_kernel(
    const int* __restrict__ src, const int* __restrict__ dst,
    const int* __restrict__ rowptr, int* cursor,
    int* __restrict__ sorted_src, int E_real, int ET)
{
    int e = blockIdx.x * blockDim.x + threadIdx.x;
    if (e >= ET) return;
    int s, d;
    if (e < E_real) { s = src[e]; d = dst[e]; }
    else            { s = e - E_real; d = s; }
    int pos = rowptr[d] + atomicAdd(&cursor[d], 1);
    sorted_src[pos] = s;
}

// ---------------------------------------------------------------------------
// 4 waves/block, ONE node per wave. Single pass (no segment-max: logits
// |a|<~0.05, exp(a)/sum == exp(a-max)/sum), no LDS, no barriers; weights
// packed so ONE shfl serves both heads; unroll x8 = 8 gathers in flight.
// xp is fp8 e4m3 -> 256 B/edge row (R14; fetch-BW bound fix).
__global__ __launch_bounds__(256) void gat_aggregate(
    const int* __restrict__ rowptr, const int* __restrict__ sorted_src,
    const float* __restrict__ a_src, const float* __restrict__ a_dst,
    const unsigned char* __restrict__ xp8, const float* __restrict__ bias_g,
    ushort* __restrict__ xg, int n)
{
    const int d = blockIdx.x * 4 + (threadIdx.x >> 6);
    if (d >= n) return;
    const int lane = threadIdx.x & 63;
    const int hsel = lane & 32;
    const int start = rowptr[d], end = rowptr[d + 1];

    const float ad0 = a_dst[2 * d + 0];
    const float ad1 = a_dst[2 * d + 1];

    float4 acc = make_float4(0.f, 0.f, 0.f, 0.f);
    float denom = 0.f;

    for (int e0 = start; e0 < end; e0 += 32) {
        const int cnt = min(32, end - e0);
        const int idx = lane & 31;
        float wsel = 0.f; int off = 0;
        if (idx < cnt) {
            int s = sorted_src[e0 + idx];
            float v0 = a_src[2 * s + 0] + ad0;
            float v1 = a_src[2 * s + 1] + ad1;
            v0 = (v0 > 0.f) ? v0 : NEG_SLOPE * v0;
            v1 = (v1 > 0.f) ? v1 : NEG_SLOPE * v1;
            wsel = (lane < 32) ? __expf(v0) : __expf(v1);
            off = s * HC;
        }
        int j = 0;
        for (; j + 8 <= cnt; j += 8) {
            float w_[8]; int o_[8];
            #pragma unroll
            for (int u = 0; u < 8; ++u) {
                w_[u] = __shfl(wsel, (j + u) + hsel);
                o_[u] = __shfl(off, j + u);
            }
            uint v_[8];
            #pragma unroll
            for (int u = 0; u < 8; ++u)
                v_[u] = *(const uint*)(xp8 + o_[u] + 4 * lane);
            #pragma unroll
            for (int u = 0; u < 8; ++u) {
                denom += w_[u];
#if FP8_HW
                f32x2 lo = __builtin_amdgcn_cvt_pk_f32_fp8((int)v_[u], false);
                f32x2 hi = __builtin_amdgcn_cvt_pk_f32_fp8((int)v_[u], true);
                acc.x += w_[u] * lo.x; acc.y += w_[u] * lo.y;
                acc.z += w_[u] * hi.x; acc.w += w_[u] * hi.y;
#else
                const float wu = w_[u] * 256.0f;
                const uint b = v_[u];
                acc.x += wu * h2f(((b & 0x80u) << 8) | ((b & 0x7fu) << 7));
                acc.y += wu * h2f((((b >> 8) & 0x80u) << 8) | (((b >> 8) & 0x7fu) << 7));
                acc.z += wu * h2f((((b >> 16) & 0x80u) << 8) | (((b >> 16) & 0x7fu) << 7));
                acc.w += wu * h2f((((b >> 24) & 0x80u) << 8) | (((b >> 24) & 0x7fu) << 7));
#endif
            }
        }
        for (; j < cnt; ++j) {
            const float w = __shfl(wsel, j + hsel);
            const int   o = __shfl(off, j);
            const uint  b = *(const uint*)(xp8 + o + 4 * lane);
            denom += w;
#if FP8_HW
            f32x2 lo = __builtin_amdgcn_cvt_pk_f32_fp8((int)b, false);
            f32x2 hi = __builtin_amdgcn_cvt_pk_f32_fp8((int)b, true);
            acc.x += w * lo.x; acc.y += w * lo.y;
            acc.z += w * hi.x; acc.w += w * hi.y;
#else
            const float wu = w * 256.0f;
            acc.x += wu * h2f(((b & 0x80u) << 8) | ((b & 0x7fu) << 7));
            acc.y += wu * h2f((((b >> 8) & 0x80u) << 8) | (((b >> 8) & 0x7fu) << 7));
            acc.z += wu * h2f((((b >> 16) & 0x80u) << 8) | (((b >> 16) & 0x7fu) << 7));
            acc.w += wu * h2f((((b >> 24) & 0x80u) << 8) | (((b >> 24) & 0x7fu) << 7));
#endif
        }
    }

    const float inv = 1.f / fmaxf(denom, 1e-16f);
    const int c = 4 * lane;
    const float4 bg = *(const float4*)(bias_g + c);
    const size_t base = ((size_t)d * HC + c) >> 2;
    ((ushort4*)xg)[base] = make_ushort4(
        f2h(acc.x * inv + bg.x), f2h(acc.y * inv + bg.y),
        f2h(acc.z * inv + bg.z), f2h(acc.w * inv + bg.w));
}

// ---------------------------------------------------------------------------
extern "C" void kernel_launch(void* const* d_in, const int* in_sizes, int n_in,
                              void* d_out, int out_size, void* d_ws, size_t ws_size,
                              hipStream_t stream)
{
    const float* z       = (const float*)d_in[0];
    const int*   ei      = (const int*)d_in[1];    // [2,E] int32
    const float* W1      = (const float*)d_in[2];
    const float* b1      = (const float*)d_in[3];
    const float* W2      = (const float*)d_in[4];
    const float* b2      = (const float*)d_in[5];
    const float* Wg      = (const float*)d_in[6];
    const float* att_src = (const float*)d_in[7];
    const float* att_dst = (const float*)d_in[8];
    const float* bias_g  = (const float*)d_in[9];
    const float* W3      = (const float*)d_in[10];
    const float* b3      = (const float*)d_in[11];
    float* out = (float*)d_out;

    const int n = N_NODES;
    const int E_real = in_sizes[1] / 2;
    const int ET = E_real + n;
    const int* src = ei;
    const int* dst = ei + E_real;

    char* p = (char*)d_ws;
    auto alloc = [&](size_t bytes) {
        char* r = p;
        p += (bytes + 63) & ~(size_t)63;
        return r;
    };
    const int np = n + 128;
    ushort* z_f16  = (ushort*)alloc((size_t)np * LATENT * 2);  // 20.6 MB
    ushort* xg_f16 = (ushort*)alloc((size_t)np * HID * 2);     // 10.3 MB
    unsigned char* xp8 = (unsigned char*)alloc((size_t)n * HC); // 5.1 MB
    ushort* W1T = (ushort*)alloc((size_t)LATENT * HID * 2);
    ushort* W2T = (ushort*)alloc((size_t)HID * 512 * 2);
    ushort* WgT = (ushort*)alloc((size_t)512 * HC * 2);
    ushort* W3T = (ushort*)alloc((size_t)HC * 512 * 2);
    float* a_src = (float*)alloc((size_t)2 * n * 4);
    float* a_dst = (float*)alloc((size_t)2 * n * 4);
    int* deg        = (int*)alloc((size_t)n * 4);
    int* rowptr     = (int*)alloc(((size_t)n + 1) * 4);
    int* cursor     = (int*)alloc((size_t)n * 4);
    int* sorted_src = (int*)alloc((size_t)ET * 4);

    const int gm128 = (n + 127) / 128;   // 157

    // prologue: z->f16 + deg/cursor/a_src/a_dst zero + 4 weight transposes
    prologue_kernel<<<CVT_BLOCKS + TR_BLOCKS, 256, 0, stream>>>(
        z, z_f16, deg, cursor, a_src, a_dst, n,
        W1, W2, Wg, W3, W1T, W2T, WgT, W3T);
    // CSR build (independent of the MLP chain until gat)
    hist_kernel<<<(ET + 255) / 256, 256, 0, stream>>>(dst, deg, E_real, ET);
    scan_kernel<<<1, 1024, 0, stream>>>(deg, rowptr, n);
    scatter_kernel<<<(ET + 255) / 256, 256, 0, stream>>>(
        src, dst, rowptr, cursor, sorted_src, E_real, ET);

    // FUSED MLP v4 (72 KB LDS, 32-row blocks, 625 blocks ~ 2.4/CU):
    // x1/x2-slabs in LDS; xp8 + attention logits out
    fused_mlp<<<n / 32, 512, 0, stream>>>(
        z_f16, W1T, b1, W2T, b2, WgT,
        att_src, att_dst, a_src, a_dst, xp8, n);

    // softmax + aggregate -> xg (f16): 4 nodes per block, one wave each
    gat_aggregate<<<(n + 3) / 4, 256, 0, stream>>>(
        rowptr, sorted_src, a_src, a_dst, xp8, bias_g, xg_f16, n);

    // GEMM4 (staged, R15-proven): out = xg @ W3 + b3, 1256 blocks
    gemm_f16<64, 3><<<gm128 * 8, 256, 0, stream>>>(
        xg_f16, W3T, b3, out, nullptr, n, 512, HC, 0);
}

// Round 12
// 290.844 us; speedup vs baseline: 1.5234x; 1.0232x over previous
//
#include <hip/hip_runtime.h>
#include <hip/hip_bf16.h>
#include <float.h>

// Problem constants (from reference)
#define N_NODES 20000
#define LATENT  512
#define HID     256
#define OUT_C   128
#define HEADS   2
#define HC      256   // HEADS*OUT_C
#define NEG_SLOPE 0.2f

typedef _Float16 half8 __attribute__((ext_vector_type(8)));  // 8 f16 = 4 VGPRs
typedef __attribute__((ext_vector_type(4))) float f32x4;
typedef __attribute__((ext_vector_type(2))) float f32x2;

// ---------------------------------------------------------------------------
__device__ __forceinline__ ushort f2h(float v) {
    _Float16 h = (_Float16)v;
    return *(ushort*)&h;
}
__device__ __forceinline__ float h2f(ushort u) {
    _Float16 h = *(_Float16*)&u;
    return (float)h;
}

// ---- fp8 e4m3 (OCP) encode/decode. Prefer HW cvt; exact bit-trick fallback.
#if __has_builtin(__builtin_amdgcn_cvt_pk_fp8_f32) && __has_builtin(__builtin_amdgcn_cvt_pk_f32_fp8)
#define FP8_HW 1
#else
#define FP8_HW 0
#endif

__device__ __forceinline__ uint f32_to_e4m3(float v) {
#if FP8_HW
    return (uint)(__builtin_amdgcn_cvt_pk_fp8_f32(v, v, 0, false) & 0xff);
#else
    _Float16 hf = (_Float16)(v * 0.00390625f);   // *2^-8
    uint hb = *(ushort*)&hf;
    uint s = (hb >> 8) & 0x80;
    uint mag = hb & 0x7fff;
    mag = (mag + 0x3f + ((mag >> 7) & 1)) >> 7;  // RNE 10->3 mantissa bits
    if (mag > 0x7e) mag = 0x7e;
    return s | mag;
#endif
}

// async global->LDS DMA, 16B per lane. LDS dest is WAVE-UNIFORM base +
// lane*16 (m104/m108); per-lane scatter impossible -> XOR chunk swizzle.
__device__ __forceinline__ void gl_lds16(const ushort* g, ushort* l) {
    __builtin_amdgcn_global_load_lds(
        (const __attribute__((address_space(1))) unsigned int*)g,
        (__attribute__((address_space(3))) unsigned int*)l, 16, 0, 0);
}

// ---------------------------------------------------------------------------
// R22 = R21 resubmitted verbatim (R21 never ran: GPU acquisition timeout;
// R20's double container failure also likely infra). Only experimental
// change vs proven R17: depth-3 P1 pipeline. The 4th 20 KB staging buffer
// fits exactly: P1 bufs (c&3)*10240 cover [0,40960) halfs = all 80 KB,
// aliasing X1/SLAB/SB which are written only after P1 fully drains.
// z streams from HBM (~900 cy); depth-2 covered ~1 segment, depth-3 ~2.
// 313 blocks x 512 threads (8 waves, wave tile 16r x 128c(P1/P3)/64c(P2)).
// LDS map (halfs): X1 [0,16384) x1 64x256 [8ch][64r][32] XOR-swz;
// SLAB [16384,24576) P2 staging 2x4096 then x2-slab [4ch][64r][32];
// SB [24576,40960) P3 staging 2x8192.
// Sync discipline (R17): buffer re-target only after a barrier proving all
// waves consumed it; counted per-wave vmcnt; boundary syncs are
// lgkmcnt(0)+s_barrier (never __syncthreads -- it drains vmcnt).
__global__ __launch_bounds__(512, 4) void fused_mlp(
    const ushort* __restrict__ z16, const ushort* __restrict__ W1T,
    const float* __restrict__ b1, const ushort* __restrict__ W2T,
    const float* __restrict__ b2, const ushort* __restrict__ WgT,
    const float* __restrict__ attS, const float* __restrict__ attD,
    float* __restrict__ aS, float* __restrict__ aD,
    unsigned char* __restrict__ xp8, int M)
{
    __shared__ ushort lds[40960];   // 80 KB

    const int t = threadIdx.x;
    const int l = t & 63;
    const int w = t >> 6;                 // 0..7
    const int wr = w & 3;                 // row group (16 rows)
    const int wc = w >> 2;                // col half
    const int lm = l & 15;
    const int q  = l >> 4;
    const int q4 = q * 4;
    const int row0 = (int)blockIdx.x * 64;
    const int lr16 = l >> 2;              // staging row within 16
    const int gsh = (((l & 3) ^ ((l >> 4) & 3)) << 3);   // global half off
    const int csw = ((q ^ ((lm >> 2) & 3)) << 3);        // frag-read swz

    constexpr int X1   = 0;
    constexpr int SLAB = 16384;
    constexpr int SB   = 24576;

    auto barsync = [&]() {
        __builtin_amdgcn_s_barrier();
        __builtin_amdgcn_sched_barrier(0);
    };

    // ---- staging (1 KB per instr = 16 rows of a 32-K chunk) ----
    auto issue1 = [&](int c) {            // z 4 instr + W1T 16 instr
        ushort* B = &lds[(c & 3) * 10240];
        const int kk = c * 32;
        #pragma unroll
        for (int u = 0; u < 3; ++u) {
            const int ii = w + u * 8;
            if (ii < 20) {
                const ushort* g = (ii < 4)
                    ? z16 + (size_t)(row0 + ii * 16 + lr16) * 512 + kk + gsh
                    : W1T + (size_t)((ii - 4) * 16 + lr16) * 512 + kk + gsh;
                gl_lds16(g, B + ii * 512);
            }
        }
    };
    auto issue2 = [&](int s, int c) {     // W2T slab rows: 8 instr (1/wave)
        ushort* B = &lds[SLAB + (c & 1) * 4096];
        gl_lds16(W2T + (size_t)(s * 128 + w * 16 + lr16) * 256 + c * 32 + gsh,
                 B + w * 512);
    };
    auto issue3 = [&](int s, int c) {     // WgT 256 rows: 16 instr (2/wave)
        ushort* B = &lds[SB + (c & 1) * 8192];
        #pragma unroll
        for (int u = 0; u < 2; ++u) {
            const int ii = w + u * 8;
            gl_lds16(WgT + (size_t)(ii * 16 + lr16) * 512 + s * 128 + c * 32 + gsh,
                     B + ii * 512);
        }
    };

    const f32x4 zf = {0.f, 0.f, 0.f, 0.f};

    // ========== phase 1: x1 = relu(z @ W1 + b1), K=512, depth-3 ==========
    f32x4 acc1[8];
    #pragma unroll
    for (int i = 0; i < 8; ++i) acc1[i] = zf;

    issue1(0); issue1(1); issue1(2);      // 4-buf, depth-3
    for (int c = 0; c < 16; ++c) {
        __builtin_amdgcn_sched_barrier(0);
        if (c + 2 < 16) {                 // in-flight {c,c+1,c+2}
            if (w < 4) asm volatile("s_waitcnt vmcnt(6)" ::: "memory");
            else       asm volatile("s_waitcnt vmcnt(4)" ::: "memory");
        } else if (c + 1 < 16) {          // in-flight {c,c+1}
            if (w < 4) asm volatile("s_waitcnt vmcnt(3)" ::: "memory");
            else       asm volatile("s_waitcnt vmcnt(2)" ::: "memory");
        } else         asm volatile("s_waitcnt vmcnt(0)" ::: "memory");
        barsync();
        if (c + 3 < 16) issue1(c + 3);
        const ushort* B = &lds[(c & 3) * 10240];
        half8 af = *(const half8*)&B[(wr * 16 + lm) * 32 + csw];
        #pragma unroll
        for (int ni = 0; ni < 8; ++ni) {
            half8 bf = *(const half8*)&B[2048 + (wc * 128 + ni * 16 + lm) * 32 + csw];
            acc1[ni] = __builtin_amdgcn_mfma_f32_16x16x32_f16(af, bf, acc1[ni], 0, 0, 0);
        }
    }
    __builtin_amdgcn_s_barrier();         // all waves done reading P1 bufs
    issue2(0, 0); issue2(0, 1);           // prefetch P2(0)
    #pragma unroll
    for (int ni = 0; ni < 8; ++ni) {      // x1 -> X1 (swizzled for A-reads)
        const int col = wc * 128 + ni * 16 + lm;
        const float bv = b1[col];
        const int ch = col >> 5, c5 = col & 31;
        #pragma unroll
        for (int r = 0; r < 4; ++r) {
            const int row = wr * 16 + q4 + r;
            const float v = fmaxf(acc1[ni][r] + bv, 0.f);
            lds[X1 + ch * 2048 + row * 32 + (((c5 >> 3) ^ q) << 3) + (c5 & 7)] = f2h(v);
        }
    }
    asm volatile("s_waitcnt lgkmcnt(0)" ::: "memory");
    barsync();

    // ========== slab loop: P2(s) x2-slab -> P3(s) acc3 += slab@Wg ==========
    f32x4 acc3[8];
    #pragma unroll
    for (int i = 0; i < 8; ++i) acc3[i] = zf;

    for (int s = 0; s < 4; ++s) {
        // ---- P2(s): slab = relu(x1 @ W2[:, s*128..+128] + b2), K=256 ----
        f32x4 acc2[4];
        #pragma unroll
        for (int i = 0; i < 4; ++i) acc2[i] = zf;

        for (int c = 0; c < 8; ++c) {
            __builtin_amdgcn_sched_barrier(0);
            if (c == 0) asm volatile("s_waitcnt vmcnt(1)" ::: "memory");
            else        asm volatile("s_waitcnt vmcnt(0)" ::: "memory");
            barsync();
            if (c >= 1 && c + 1 < 8) issue2(s, c + 1);   // buf consumed @ bar
            if (c == 7) { issue3(s, 0); issue3(s, 1); }  // SB bufs long dead
            const ushort* Bf = &lds[SLAB + (c & 1) * 4096];
            half8 af = *(const half8*)&lds[X1 + c * 2048 + (wr * 16 + lm) * 32 + csw];
            #pragma unroll
            for (int ni = 0; ni < 4; ++ni) {
                half8 bf = *(const half8*)&Bf[(wc * 64 + ni * 16 + lm) * 32 + csw];
                acc2[ni] = __builtin_amdgcn_mfma_f32_16x16x32_f16(af, bf, acc2[ni], 0, 0, 0);
            }
        }
        __builtin_amdgcn_s_barrier();     // all compute2(7) done
        #pragma unroll
        for (int ni = 0; ni < 4; ++ni) {  // slab -> SLAB (swizzled)
            const int c7 = wc * 64 + ni * 16 + lm;
            const float bv = b2[s * 128 + c7];
            const int ch = c7 >> 5, c5 = c7 & 31;
            #pragma unroll
            for (int r = 0; r < 4; ++r) {
                const int row = wr * 16 + q4 + r;
                const float v = fmaxf(acc2[ni][r] + bv, 0.f);
                lds[SLAB + ch * 2048 + row * 32 + (((c5 >> 3) ^ q) << 3) + (c5 & 7)] = f2h(v);
            }
        }
        asm volatile("s_waitcnt lgkmcnt(0)" ::: "memory");
        barsync();

        // ---- P3(s): acc3 += slab @ Wg[s*128..+128, :], K=128 ----
        for (int c = 0; c < 4; ++c) {
            __builtin_amdgcn_sched_barrier(0);
            if (c == 0)                asm volatile("s_waitcnt vmcnt(2)" ::: "memory");
            else if (c == 3 && s < 3)  asm volatile("s_waitcnt vmcnt(1)" ::: "memory");
            else                       asm volatile("s_waitcnt vmcnt(0)" ::: "memory");
            barsync();
            if (c == 1) issue3(s, 2);                    // buf0 consumed @ bar
            if (c == 2) { issue3(s, 3);                  // buf1 consumed @ bar
                          if (s < 3) issue2(s + 1, 0); } // SLAB ch0-1 consumed
            const ushort* Bf = &lds[SB + (c & 1) * 8192];
            half8 af = *(const half8*)&lds[SLAB + c * 2048 + (wr * 16 + lm) * 32 + csw];
            #pragma unroll
            for (int ni = 0; ni < 8; ++ni) {
                half8 bf = *(const half8*)&Bf[(wc * 128 + ni * 16 + lm) * 32 + csw];
                acc3[ni] = __builtin_amdgcn_mfma_f32_16x16x32_f16(af, bf, acc3[ni], 0, 0, 0);
            }
        }
        __builtin_amdgcn_s_barrier();     // all compute3(3) done (SLAB free)
        if (s < 3) issue2(s + 1, 1);
        __builtin_amdgcn_sched_barrier(0);
    }

    // ============ epilogue: xp8 = fp8(acc3) + att logits ============
    const int h = wc;
    float asv[8], adv[8];
    #pragma unroll
    for (int ni = 0; ni < 8; ++ni) {
        const int col = wc * 128 + ni * 16 + lm;
        asv[ni] = attS[col];
        adv[ni] = attD[col];
    }
    #pragma unroll
    for (int r = 0; r < 4; ++r) {
        const int row = row0 + wr * 16 + q4 + r;
        float ps = 0.f, pd = 0.f;
        #pragma unroll
        for (int ni = 0; ni < 8; ++ni) {
            const float v = acc3[ni][r];
            ps += v * asv[ni];
            pd += v * adv[ni];
            if (row < M)
                xp8[(size_t)row * HC + wc * 128 + ni * 16 + lm] =
                    (unsigned char)f32_to_e4m3(v);
        }
        #pragma unroll
        for (int off = 8; off > 0; off >>= 1) {
            ps += __shfl_xor(ps, off);
            pd += __shfl_xor(pd, off);
        }
        if (lm == 0 && row < M) {
            atomicAdd(&aS[2 * row + h], ps);
            atomicAdd(&aD[2 * row + h], pd);
        }
    }
}

// ---------------------------------------------------------------------------
// fp16 MFMA GEMM (GEMM4 only; R15-proven). Block tile 128x64, 4 waves,
// BK=32, 3-buffer counted-vmcnt pipeline, XCD-aware bijective swizzle.
template<int BN, int LOGNBY>
__global__ __launch_bounds__(256, 4) void gemm_f16(
    const ushort* __restrict__ A, const ushort* __restrict__ BT,
    const float* __restrict__ bias,
    float* __restrict__ Cf, ushort* __restrict__ Ch,
    int M, int N, int K, int relu)
{
    static_assert(BN == 64, "vmcnt immediates assume 3 DMAs/chunk");
    constexpr int NI  = BN / 32;
    constexpr int BUF = 4096 + BN * 32;
    __shared__ ushort lds[3 * BUF];

    const int t = threadIdx.x;
    const int l = t & 63;
    const int w = t >> 6;
    const int wm = (w >> 1) * 64;
    const int wn = (w & 1) * (BN / 2);
    const int lm = l & 15;
    const int q  = l >> 4;
    const int q4 = q * 4;

    const int T  = (int)gridDim.x;
    const int qq = T >> 3, rr = T & 7;
    const int kx = (int)blockIdx.x & 7;
    const int jx = (int)blockIdx.x >> 3;
    const int lin = kx * qq + (kx < rr ? kx : rr) + jx;
    const int row0 = (lin >> LOGNBY) * 128;
    const int col0 = (lin & ((1 << LOGNBY) - 1)) * BN;

    const int jr0 = w * 16 + (l >> 2);
    const int gsh = (((l & 3) ^ ((l >> 4) & 3)) << 3);
    const ushort* gA0 = A + (size_t)(row0 + jr0) * K + gsh;
    const ushort* gA1 = gA0 + (size_t)64 * K;
    const ushort* gB0 = BT + (size_t)(col0 + jr0) * K + gsh;
    const int dA0 = w * 512, dA1 = (4 + w) * 512;
    const int dB0 = 4096 + w * 512;

    const int csw = ((q ^ ((lm >> 2) & 3)) << 3);

    const f32x4 zf = {0.f, 0.f, 0.f, 0.f};
    f32x4 acc[4][NI];
    #pragma unroll
    for (int i = 0; i < 4; ++i)
        #pragma unroll
        for (int j = 0; j < NI; ++j) acc[i][j] = zf;

    const int NC = K >> 5;

    auto issue = [&](int c) {
        ushort* B = lds + (size_t)(c % 3) * BUF;
        const int kk = c * 32;
        gl_lds16(gA0 + kk, B + dA0);
        gl_lds16(gA1 + kk, B + dA1);
        gl_lds16(gB0 + kk, B + dB0);
    };

    auto compute = [&](int c) {
        const ushort* B = lds + (size_t)(c % 3) * BUF;
        half8 bf[NI];
        #pragma unroll
        for (int ni = 0; ni < NI; ++ni) {
            const int boff = (wn + ni * 16 + lm) * 32 + csw;
            bf[ni] = *(const half8*)&B[4096 + boff];
        }
        #pragma unroll
        for (int mi = 0; mi < 4; ++mi) {
            const int aoff = (wm + mi * 16 + lm) * 32 + csw;
            half8 af = *(const half8*)&B[aoff];
            #pragma unroll
            for (int ni = 0; ni < NI; ++ni)
                acc[mi][ni] = __builtin_amdgcn_mfma_f32_16x16x32_f16(
                    af, bf[ni], acc[mi][ni], 0, 0, 0);
        }
    };

    issue(0); issue(1);
    for (int c = 0; c < NC; ++c) {
        __builtin_amdgcn_sched_barrier(0);
        if (c + 1 < NC) asm volatile("s_waitcnt vmcnt(3)" ::: "memory");
        else            asm volatile("s_waitcnt vmcnt(0)" ::: "memory");
        __builtin_amdgcn_s_barrier();
        __builtin_amdgcn_sched_barrier(0);
        if (c + 2 < NC) issue(c + 2);
        compute(c);
    }

    #pragma unroll
    for (int mi = 0; mi < 4; ++mi) {
        #pragma unroll
        for (int ni = 0; ni < NI; ++ni) {
            const int col = col0 + wn + ni * 16 + lm;
            const float bv = bias ? bias[col] : 0.f;
            #pragma unroll
            for (int r = 0; r < 4; ++r) {
                const int row = row0 + wm + mi * 16 + q4 + r;
                if (row >= M) continue;
                float v = acc[mi][ni][r] + bv;
                if (relu) v = fmaxf(v, 0.f);
                const size_t idx = (size_t)row * N + col;
                if (Cf) Cf[idx] = v;
                if (Ch) Ch[idx] = f2h(v);
            }
        }
    }
}

// ---------------------------------------------------------------------------
// Fused prologue, one launch:
//   blocks [0,10000):      z fp32 -> f16 (x4) + deg/cursor/a_src/a_dst zero
//   blocks [10000,12048):  4 weight transposes W[K,N] fp32 -> WT[N,K] f16
#define CVT_BLOCKS 10000
#define TR_BLOCKS  2048
__global__ __launch_bounds__(256) void prologue_kernel(
    const float* __restrict__ z, ushort* __restrict__ z_f16,
    int* deg, int* cursor, float* aS, float* aD, int n,
    const float* __restrict__ W1, const float* __restrict__ W2,
    const float* __restrict__ Wg, const float* __restrict__ W3,
    ushort* __restrict__ T1, ushort* __restrict__ T2,
    ushort* __restrict__ Tg, ushort* __restrict__ T3)
{
    const int b = blockIdx.x;
    if (b < CVT_BLOCKS) {
        int i = b * 256 + threadIdx.x;
        if (i < n) {
            deg[i] = 0; cursor[i] = 0;
            ((float2*)aS)[i] = make_float2(0.f, 0.f);
            ((float2*)aD)[i] = make_float2(0.f, 0.f);
        }
        float4 v = ((const float4*)z)[i];
        ((ushort4*)z_f16)[i] = make_ushort4(f2h(v.x), f2h(v.y), f2h(v.z), f2h(v.w));
    } else {
        int idx = (b - CVT_BLOCKS) * 256 + threadIdx.x;
        int which = idx >> 17, i = idx & 131071;
        const float* W; ushort* T; int K, N;
        if (which == 0)      { W = W1; T = T1; K = 512; N = 256; }
        else if (which == 1) { W = W2; T = T2; K = 256; N = 512; }
        else if (which == 2) { W = Wg; T = Tg; K = 512; N = 256; }
        else                 { W = W3; T = T3; K = 256; N = 512; }
        int k = i / N, nn = i - k * N;
        T[(size_t)nn * K + k] = f2h(W[i]);
    }
}

// ---------------------------------------------------------------------------
__global__ __launch_bounds__(256) void hist_kernel(
    const int* __restrict__ dst, int* deg, int E_real, int ET)
{
    int e = blockIdx.x * blockDim.x + threadIdx.x;
    if (e >= ET) return;
    int d = (e < E_real) ? dst[e] : (e - E_real);
    atomicAdd(&deg[d], 1);
}

// Exclusive scan deg[0..n) -> rowptr[0..n]; single block, 1024 threads.
__global__ __launch_bounds__(1024) void scan_kernel(
    const int* __restrict__ deg, int* __restrict__ rowptr, int n)
{
    __shared__ int part[1024];
    const int t = threadIdx.x;
    const int chunk = (n + 1023) / 1024;
    const int lo = t * chunk;
    const int hi = min(lo + chunk, n);
    int s = 0;
    for (int i = lo; i < hi; ++i) s += deg[i];
    part[t] = s;
    __syncthreads();
    #pragma unroll
    for (int off = 1; off < 1024; off <<= 1) {
        int add = (t >= off) ? part[t - off] : 0;
        __syncthreads();
        part[t] += add;
        __syncthreads();
    }
    int run = part[t] - s;   // exclusive prefix of this thread's chunk
    for (int i = lo; i < hi; ++i) { rowptr[i] = run; run += deg[i]; }
    if (t == 1023) rowptr[n] = part[1023];
}

__global__ __launch_bounds__(256) void scatter_kernel(
    const int* __restrict__ src, const int* __restrict__ dst,
    const int* __restrict__ rowptr, int* cursor,
    int* __restrict__ sorted_src, int E_real, int ET)
{
    int e = blockIdx.x * blockDim.x + threadIdx.x;
    if (e >= ET) return;
    int s, d;
    if (e < E_real) { s = src[e]; d = dst[e]; }
    else            { s = e - E_real; d = s; }
    int pos = rowptr[d] + atomicAdd(&cursor[d], 1);
    sorted_src[pos] = s;
}

// ---------------------------------------------------------------------------
// 4 waves/block, ONE node per wave. Single pass (no segment-max: logits
// |a|<~0.05, exp(a)/sum == exp(a-max)/sum), no LDS, no barriers; weights
// packed so ONE shfl serves both heads; unroll x8 = 8 gathers in flight.
// xp is fp8 e4m3 -> 256 B/edge row (R14; fetch-BW bound fix).
__global__ __launch_bounds__(256) void gat_aggregate(
    const int* __restrict__ rowptr, const int* __restrict__ sorted_src,
    const float* __restrict__ a_src, const float* __restrict__ a_dst,
    const unsigned char* __restrict__ xp8, const float* __restrict__ bias_g,
    ushort* __restrict__ xg, int n)
{
    const int d = blockIdx.x * 4 + (threadIdx.x >> 6);
    if (d >= n) return;
    const int lane = threadIdx.x & 63;
    const int hsel = lane & 32;
    const int start = rowptr[d], end = rowptr[d + 1];

    const float ad0 = a_dst[2 * d + 0];
    const float ad1 = a_dst[2 * d + 1];

    float4 acc = make_float4(0.f, 0.f, 0.f, 0.f);
    float denom = 0.f;

    for (int e0 = start; e0 < end; e0 += 32) {
        const int cnt = min(32, end - e0);
        const int idx = lane & 31;
        float wsel = 0.f; int off = 0;
        if (idx < cnt) {
            int s = sorted_src[e0 + idx];
            float v0 = a_src[2 * s + 0] + ad0;
            float v1 = a_src[2 * s + 1] + ad1;
            v0 = (v0 > 0.f) ? v0 : NEG_SLOPE * v0;
            v1 = (v1 > 0.f) ? v1 : NEG_SLOPE * v1;
            wsel = (lane < 32) ? __expf(v0) : __expf(v1);
            off = s * HC;
        }
        int j = 0;
        for (; j + 8 <= cnt; j += 8) {
            float w_[8]; int o_[8];
            #pragma unroll
            for (int u = 0; u < 8; ++u) {
                w_[u] = __shfl(wsel, (j + u) + hsel);
                o_[u] = __shfl(off, j + u);
            }
            uint v_[8];
            #pragma unroll
            for (int u = 0; u < 8; ++u)
                v_[u] = *(const uint*)(xp8 + o_[u] + 4 * lane);
            #pragma unroll
            for (int u = 0; u < 8; ++u) {
                denom += w_[u];
#if FP8_HW
                f32x2 lo = __builtin_amdgcn_cvt_pk_f32_fp8((int)v_[u], false);
                f32x2 hi = __builtin_amdgcn_cvt_pk_f32_fp8((int)v_[u], true);
                acc.x += w_[u] * lo.x; acc.y += w_[u] * lo.y;
                acc.z += w_[u] * hi.x; acc.w += w_[u] * hi.y;
#else
                const float wu = w_[u] * 256.0f;
                const uint b = v_[u];
                acc.x += wu * h2f(((b & 0x80u) << 8) | ((b & 0x7fu) << 7));
                acc.y += wu * h2f((((b >> 8) & 0x80u) << 8) | (((b >> 8) & 0x7fu) << 7));
                acc.z += wu * h2f((((b >> 16) & 0x80u) << 8) | (((b >> 16) & 0x7fu) << 7));
                acc.w += wu * h2f((((b >> 24) & 0x80u) << 8) | (((b >> 24) & 0x7fu) << 7));
#endif
            }
        }
        for (; j < cnt; ++j) {
            const float w = __shfl(wsel, j + hsel);
            const int   o = __shfl(off, j);
            const uint  b = *(const uint*)(xp8 + o + 4 * lane);
            denom += w;
#if FP8_HW
            f32x2 lo = __builtin_amdgcn_cvt_pk_f32_fp8((int)b, false);
            f32x2 hi = __builtin_amdgcn_cvt_pk_f32_fp8((int)b, true);
            acc.x += w * lo.x; acc.y += w * lo.y;
            acc.z += w * hi.x; acc.w += w * hi.y;
#else
            const float wu = w * 256.0f;
            acc.x += wu * h2f(((b & 0x80u) << 8) | ((b & 0x7fu) << 7));
            acc.y += wu * h2f((((b >> 8) & 0x80u) << 8) | (((b >> 8) & 0x7fu) << 7));
            acc.z += wu * h2f((((b >> 16) & 0x80u) << 8) | (((b >> 16) & 0x7fu) << 7));
            acc.w += wu * h2f((((b >> 24) & 0x80u) << 8) | (((b >> 24) & 0x7fu) << 7));
#endif
        }
    }

    const float inv = 1.f / fmaxf(denom, 1e-16f);
    const int c = 4 * lane;
    const float4 bg = *(const float4*)(bias_g + c);
    const size_t base = ((size_t)d * HC + c) >> 2;
    ((ushort4*)xg)[base] = make_ushort4(
        f2h(acc.x * inv + bg.x), f2h(acc.y * inv + bg.y),
        f2h(acc.z * inv + bg.z), f2h(acc.w * inv + bg.w));
}

// ---------------------------------------------------------------------------
extern "C" void kernel_launch(void* const* d_in, const int* in_sizes, int n_in,
                              void* d_out, int out_size, void* d_ws, size_t ws_size,
                              hipStream_t stream)
{
    const float* z       = (const float*)d_in[0];
    const int*   ei      = (const int*)d_in[1];    // [2,E] int32
    const float* W1      = (const float*)d_in[2];
    const float* b1      = (const float*)d_in[3];
    const float* W2      = (const float*)d_in[4];
    const float* b2      = (const float*)d_in[5];
    const float* Wg      = (const float*)d_in[6];
    const float* att_src = (const float*)d_in[7];
    const float* att_dst = (const float*)d_in[8];
    const float* bias_g  = (const float*)d_in[9];
    const float* W3      = (const float*)d_in[10];
    const float* b3      = (const float*)d_in[11];
    float* out = (float*)d_out;

    const int n = N_NODES;
    const int E_real = in_sizes[1] / 2;
    const int ET = E_real + n;
    const int* src = ei;
    const int* dst = ei + E_real;

    char* p = (char*)d_ws;
    auto alloc = [&](size_t bytes) {
        char* r = p;
        p += (bytes + 63) & ~(size_t)63;
        return r;
    };
    const int np = n + 128;
    ushort* z_f16  = (ushort*)alloc((size_t)np * LATENT * 2);  // 20.6 MB
    ushort* xg_f16 = (ushort*)alloc((size_t)np * HID * 2);     // 10.3 MB
    unsigned char* xp8 = (unsigned char*)alloc((size_t)n * HC); // 5.1 MB
    ushort* W1T = (ushort*)alloc((size_t)LATENT * HID * 2);
    ushort* W2T = (ushort*)alloc((size_t)HID * 512 * 2);
    ushort* WgT = (ushort*)alloc((size_t)512 * HC * 2);
    ushort* W3T = (ushort*)alloc((size_t)HC * 512 * 2);
    float* a_src = (float*)alloc((size_t)2 * n * 4);
    float* a_dst = (float*)alloc((size_t)2 * n * 4);
    int* deg        = (int*)alloc((size_t)n * 4);
    int* rowptr     = (int*)alloc(((size_t)n + 1) * 4);
    int* cursor     = (int*)alloc((size_t)n * 4);
    int* sorted_src = (int*)alloc((size_t)ET * 4);

    const int gm128 = (n + 127) / 128;   // 157

    // prologue: z->f16 + deg/cursor/a_src/a_dst zero + 4 weight transposes
    prologue_kernel<<<CVT_BLOCKS + TR_BLOCKS, 256, 0, stream>>>(
        z, z_f16, deg, cursor, a_src, a_dst, n,
        W1, W2, Wg, W3, W1T, W2T, WgT, W3T);
    // CSR build (proven separate kernels)
    hist_kernel<<<(ET + 255) / 256, 256, 0, stream>>>(dst, deg, E_real, ET);
    scan_kernel<<<1, 1024, 0, stream>>>(deg, rowptr, n);
    scatter_kernel<<<(ET + 255) / 256, 256, 0, stream>>>(
        src, dst, rowptr, cursor, sorted_src, E_real, ET);

    // FUSED MLP (R17 structure, depth-3 P1): x1/x2-slabs in LDS;
    // xp8 + attention logits out
    fused_mlp<<<(n + 63) / 64, 512, 0, stream>>>(
        z_f16, W1T, b1, W2T, b2, WgT,
        att_src, att_dst, a_src, a_dst, xp8, n);

    // softmax + aggregate -> xg (f16): 4 nodes per block, one wave each
    gat_aggregate<<<(n + 3) / 4, 256, 0, stream>>>(
        rowptr, sorted_src, a_src, a_dst, xp8, bias_g, xg_f16, n);

    // GEMM4 (staged, R15-proven): out = xg @ W3 + b3, 1256 blocks
    gemm_f16<64, 3><<<gm128 * 8, 256, 0, stream>>>(
        xg_f16, W3T, b3, out, nullptr, n, 512, HC, 0);
}